// Round 1
// baseline (105.866 us; speedup 1.0000x reference)
//
#include <hip/hip_runtime.h>
#include <cmath>

#define NROWS 4096
#define TLEN  1024
#define LT0   895      // first t stored for level/trend tail (COND-1)
#define ST0   889      // first t stored for seas tail (889 = 896-7)
#define LTN   129      // number of level/trend tail entries
#define STN   135      // number of seas tail entries
#define PR_F4 (NROWS * 129 * 14)   // pr float4 count = 7,397,376

__device__ __forceinline__ float sigmoidf_(float x) {
    return 1.0f / (1.0f + expf(-x));
}

__device__ __forceinline__ float f4c(const float4& v, int k) {
    switch (k & 3) { case 0: return v.x; case 1: return v.y; case 2: return v.z; default: return v.w; }
}

template<bool TAIL>
__device__ __forceinline__ void group28(
    int g, int n,
    const float4* __restrict__ qv, float4* __restrict__ smv,
    float& L, float& B, float (&sr)[7], float& dsum,
    float4 (&cur)[7],
    float a, float ia, float b, float ib, float c, float ic,
    float* __restrict__ Lt, float* __restrict__ Tt, float* __restrict__ St)
{
    float4 nxt[7];
    const bool pf = (g < 35);
    #pragma unroll
    for (int i = 0; i < 7; ++i) { if (pf) nxt[i] = qv[(g + 1) * 7 + i]; }

    const int tbase = g * 28;
    float4 sq;
    #pragma unroll
    for (int k = 0; k < 28; ++k) {
        const float y = f4c(cur[k >> 2], k);
        const int si = k % 7;                 // compile-time after unroll
        const float pred  = L + B;
        const float level = a * y + ia * pred;
        const float d     = level - L;
        dsum += fabsf(d);
        const float trend = b * d + ib * B;
        const float e     = y - pred;
        const float sn    = c * e + ic * sr[si];
        const float smval = (y - level) - sn;
        sr[si] = sn;
        L = level; B = trend;
        switch (k & 3) { case 0: sq.x = smval; break; case 1: sq.y = smval; break;
                         case 2: sq.z = smval; break; default: sq.w = smval; }
        if ((k & 3) == 3) smv[g * 7 + (k >> 2)] = sq;
        if (TAIL) {
            const int t = tbase + k;
            if (t >= ST0) St[(size_t)(t - ST0) * NROWS + n] = sn;
            if (t >= LT0) {
                Lt[(size_t)(t - LT0) * NROWS + n] = level;
                Tt[(size_t)(t - LT0) * NROWS + n] = trend;
            }
        }
    }
    #pragma unroll
    for (int i = 0; i < 7; ++i) { if (pf) cur[i] = nxt[i]; }
}

__global__ __launch_bounds__(64)
void es_scan(const float* __restrict__ query,
             const float* __restrict__ params,
             float* __restrict__ sm,
             float* __restrict__ diffs,
             float* __restrict__ Lt,   // [129][4096]
             float* __restrict__ Tt,   // [129][4096]
             float* __restrict__ St)   // [135][4096]
{
    const int n = blockIdx.x * 64 + threadIdx.x;

    const float* pp = params + n * 12;
    float L = pp[0];
    const float a = sigmoidf_(pp[1]);
    float B = pp[2];
    const float b = sigmoidf_(pp[3]);
    const float c = pp[4];                 // NOT sigmoided (reference)
    float sr[7];
    #pragma unroll
    for (int i = 0; i < 7; ++i) sr[i] = sigmoidf_(pp[5 + i]);
    const float ia = 1.0f - a, ib = 1.0f - b, ic = 1.0f - c;

    const float4* qv = reinterpret_cast<const float4*>(query + (size_t)n * TLEN);
    float4* smv      = reinterpret_cast<float4*>(sm + (size_t)n * TLEN);

    float dsum = 0.0f;
    float4 cur[7];
    #pragma unroll
    for (int i = 0; i < 7; ++i) cur[i] = qv[i];

    // groups of 28 steps (= lcm(4,7)); t in [0, 1008)
    for (int g = 0; g < 31; ++g)
        group28<false>(g, n, qv, smv, L, B, sr, dsum, cur, a, ia, b, ib, c, ic, Lt, Tt, St);
    for (int g = 31; g < 36; ++g)
        group28<true>(g, n, qv, smv, L, B, sr, dsum, cur, a, ia, b, ib, c, ic, Lt, Tt, St);

    // remainder: t = 1008..1023 (season phase continues at sr[0] since 1008 % 7 == 0)
    {
        float4 r[4];
        #pragma unroll
        for (int i = 0; i < 4; ++i) r[i] = qv[252 + i];
        float4 sq;
        #pragma unroll
        for (int k = 0; k < 16; ++k) {
            const float y = f4c(r[k >> 2], k);
            const int si = k % 7;
            const float pred  = L + B;
            const float level = a * y + ia * pred;
            const float d     = level - L;
            dsum += fabsf(d);
            const float trend = b * d + ib * B;
            const float e     = y - pred;
            const float sn    = c * e + ic * sr[si];
            const float smval = (y - level) - sn;
            sr[si] = sn;
            L = level; B = trend;
            switch (k & 3) { case 0: sq.x = smval; break; case 1: sq.y = smval; break;
                             case 2: sq.z = smval; break; default: sq.w = smval; }
            if ((k & 3) == 3) smv[252 + (k >> 2)] = sq;
            const int t = 1008 + k;
            St[(size_t)(t - ST0) * NROWS + n] = sn;
            Lt[(size_t)(t - LT0) * NROWS + n] = level;
            Tt[(size_t)(t - LT0) * NROWS + n] = trend;
        }
    }

    diffs[n] = dsum * (1.0f / 1024.0f);
}

__global__ __launch_bounds__(256)
void es_pr(const float* __restrict__ Lt,
           const float* __restrict__ Tt,
           const float* __restrict__ St,
           float4* __restrict__ pr)
{
    const int q = blockIdx.x * 256 + threadIdx.x;
    if (q >= PR_F4) return;
    const int h4 = q % 14;
    const int r  = q / 14;
    const int s  = r % 129;
    const int n  = r / 129;

    const float L = Lt[(size_t)s * NROWS + n];
    const float T = Tt[(size_t)s * NROWS + n];

    const int hb = h4 * 4;        // h = hb..hb+3; horizon = h+1
    int m0 = hb % 7;
    int m1 = m0 + 1; if (m1 >= 7) m1 -= 7;
    int m2 = m0 + 2; if (m2 >= 7) m2 -= 7;
    int m3 = m0 + 3; if (m3 >= 7) m3 -= 7;

    float4 o;
    o.x = (L + T * (float)(hb + 1)) + St[(size_t)(s + m0) * NROWS + n];
    o.y = (L + T * (float)(hb + 2)) + St[(size_t)(s + m1) * NROWS + n];
    o.z = (L + T * (float)(hb + 3)) + St[(size_t)(s + m2) * NROWS + n];
    o.w = (L + T * (float)(hb + 4)) + St[(size_t)(s + m3) * NROWS + n];
    pr[q] = o;
}

extern "C" void kernel_launch(void* const* d_in, const int* in_sizes, int n_in,
                              void* d_out, int out_size, void* d_ws, size_t ws_size,
                              hipStream_t stream) {
    const float* query  = (const float*)d_in[0];
    const float* params = (const float*)d_in[1];

    float* out   = (float*)d_out;
    float* sm    = out;                                  // 4096*1024
    float* pr    = out + (size_t)NROWS * TLEN;           // 4096*129*56
    float* diffs = pr  + (size_t)NROWS * 129 * 56;       // 4096

    float* Lt = (float*)d_ws;                            // [129][4096]
    float* Tt = Lt + (size_t)LTN * NROWS;                // [129][4096]
    float* St = Tt + (size_t)LTN * NROWS;                // [135][4096]

    hipLaunchKernelGGL(es_scan, dim3(64), dim3(64), 0, stream,
                       query, params, sm, diffs, Lt, Tt, St);
    hipLaunchKernelGGL(es_pr, dim3(PR_F4 / 256), dim3(256), 0, stream,
                       Lt, Tt, St, (float4*)pr);
}